// Round 1
// 186.253 us; speedup vs baseline: 1.0178x; 1.0178x over previous
//
#include <hip/hip_runtime.h>
#include <math.h>

namespace {
constexpr int kB = 4;
constexpr int kS = 4096;
constexpr int kD = 1024;
constexpr int kM = 128;
constexpr int kC = 64;           // chunk length
constexpr int kNC = kS / kC;     // 64 chunks per batch
constexpr int kRS = kB * kS;     // 16384 rows
constexpr float kLR = 0.01f;
constexpr float kLog2d = -0.0144995696f;   // log2(0.99)
}

typedef __bf16 bf16x8 __attribute__((ext_vector_type(8)));
typedef float  f32x4  __attribute__((ext_vector_type(4)));
typedef unsigned short u16;
typedef unsigned int   u32;

__device__ __forceinline__ u16 f2bf(float f) {
  u32 x = __float_as_uint(f);
  u32 r = (x + 0x7fffu + ((x >> 16) & 1u)) >> 16;   // RNE
  return (u16)r;
}

__device__ __forceinline__ float bf2f(u16 h) {
  return __uint_as_float(((u32)h) << 16);
}

__device__ __forceinline__ void gl_lds16(const void* g, void* l) {
  __builtin_amdgcn_global_load_lds(
      (const __attribute__((address_space(1))) void*)g,
      (__attribute__((address_space(3))) void*)l, 16, 0, 0);
}

__device__ __forceinline__ f32x4 mf(bf16x8 a, bf16x8 b, f32x4 c) {
  return __builtin_amdgcn_mfma_f32_16x16x32_bf16(a, b, c, 0, 0, 0);
}

__device__ __forceinline__ uint4 pack8(float4 a, float4 b) {
  union { u16 h[8]; uint4 u; } r;
  r.h[0] = f2bf(a.x); r.h[1] = f2bf(a.y); r.h[2] = f2bf(a.z); r.h[3] = f2bf(a.w);
  r.h[4] = f2bf(b.x); r.h[5] = f2bf(b.y); r.h[6] = f2bf(b.z); r.h[7] = f2bf(b.w);
  return r.u;
}

// Fragment-panel layouts: 1 KiB panel = 16 rows x 32 cols bf16; element (r,c)
// at byte ((c>>3)&3)*256 + (r&15)*16 + (c&7)*2.  A wave ds_read_b128 of one
// fragment (lane -> qd*256 + fr*16) covers a contiguous 1 KiB -> conflict-free.
__device__ __forceinline__ int fo64x128(int r, int c) {   // 64 rows x 128 cols
  return ((r >> 4) * 4 + (c >> 5)) * 1024 + ((c >> 3) & 3) * 256 + (r & 15) * 16 + (c & 7) * 2;
}
__device__ __forceinline__ int fo128x64(int r, int c) {   // 128 rows x 64 cols
  return ((r >> 4) * 2 + (c >> 5)) * 1024 + ((c >> 3) & 3) * 256 + (r & 15) * 16 + (c & 7) * 2;
}
__device__ __forceinline__ int fo64x64(int r, int c) {    // 64 rows x 64 cols
  return ((r >> 4) * 2 + (c >> 5)) * 1024 + ((c >> 3) & 3) * 256 + (r & 15) * 16 + (c & 7) * 2;
}

// ---------------------------------------------------------------------------
// cast Wk|Wv|Wq (concat -> Wkvq[384][1024]) and Wo -> Woh[1024][128], bf16
// ---------------------------------------------------------------------------
__global__ __launch_bounds__(256)
void cast_w_kernel(const float* __restrict__ Wk, const float* __restrict__ Wv,
                   const float* __restrict__ Wq, const float* __restrict__ Wo,
                   u16* __restrict__ Wkvq, u16* __restrict__ Woh)
{
  int i = (blockIdx.x * 256 + threadIdx.x) * 4;   // < 524288
  const float* src;
  u16* dst;
  if (i < 393216) {
    src = (i < 131072) ? Wk + i : (i < 262144) ? Wv + (i - 131072) : Wq + (i - 262144);
    dst = Wkvq + i;
  } else {
    src = Wo + (i - 393216);
    dst = Woh + (i - 393216);
  }
  float4 v = *(const float4*)src;
  ushort4 o;
  o.x = f2bf(v.x); o.y = f2bf(v.y); o.z = f2bf(v.z); o.w = f2bf(v.w);
  *(ushort4*)dst = o;
}

// ---------------------------------------------------------------------------
// Kernel A: fused projection + chunk-intra. 512 threads (8 waves), one block
// per (chunk c, batch b). Projection: double-buffered stage-ahead K-loop
// (K-step 32, single barrier per step). All MFMA operands in fragment-panel
// LDS layouts (conflict-free ds_read_b128).
// LDS byte map (64 KiB):
//   staging: As[2] @ 0 / 4096 (4 KiB each), Bs[2] @ 8192 / 32768 (24 KiB each)
//   intra (after proj): Qs @ 0 (16K), Ks @ 16384 (16K), Vt @ 32768 (16K),
//                       Kwt @ 49152 (16K); At @ 16384 (8K, overwrites Ks).
// ---------------------------------------------------------------------------
__global__ __launch_bounds__(512)
void fused_proj_intra(const float* __restrict__ x, const u16* __restrict__ Wkvq,
                      const float* __restrict__ bk, const float* __restrict__ bv,
                      const float* __restrict__ bq,
                      u16* __restrict__ Qg, u16* __restrict__ O1g,
                      float* __restrict__ SU)
{
  __shared__ __align__(16) u16 L[32768];   // 64 KiB
  const int c = blockIdx.x, b = blockIdx.y;
  const int R0 = b * kS + c * kC;
  const int tid = threadIdx.x, w = tid >> 6, lane = tid & 63;
  const int fr = lane & 15, qd = lane >> 4;

  constexpr int As0 = 0, As1 = 4096, Bs0 = 8192, Bs1 = 32768;
  constexpr int QsB = 0, KsB = 16384, VtB = 32768, KwB = 49152, AtB = 16384;

  // ---------------- projection ----------------
  f32x4 acc[4][3] = {};
  const int xrow = tid >> 2, xslot = tid & 3;
  const float* xp = x;
  if (tid < 256) xp = x + (size_t)(R0 + xrow) * kD + xslot * 8;
  const int xoff = (xrow >> 4) * 1024 + xslot * 256 + (xrow & 15) * 16;  // byte in As
  // per-lane global source in fragment order: row pn*16+fr, col k0+qd*8
  const u16* wg = Wkvq + (size_t)(48 * w + fr) * kD + qd * 8;

  float4 xa, xb;
  // prologue: stage step 0, prefetch x regs for step 1
  if (tid < 256) {
    float4 a0 = *(const float4*)xp;
    float4 b0 = *(const float4*)(xp + 4);
    *(uint4*)&L[(As0 + xoff) >> 1] = pack8(a0, b0);
  }
#pragma unroll
  for (int j = 0; j < 3; ++j)
    gl_lds16(wg + (size_t)j * 16 * kD, &L[(Bs0 + (3 * w + j) * 1024) >> 1]);
  if (tid < 256) { xa = *(const float4*)(xp + 32); xb = *(const float4*)(xp + 36); }
  __syncthreads();

#pragma unroll 2
  for (int i = 0; i < 32; ++i) {
    const int AsC = (i & 1) ? As1 : As0, BsC = (i & 1) ? Bs1 : Bs0;
    const int AsN = (i & 1) ? As0 : As1, BsN = (i & 1) ? Bs0 : Bs1;
    if (i < 31) {
      const int k1 = (i + 1) * 32;
#pragma unroll
      for (int j = 0; j < 3; ++j)
        gl_lds16(wg + k1 + (size_t)j * 16 * kD, &L[(BsN + (3 * w + j) * 1024) >> 1]);
      if (tid < 256) {
        *(uint4*)&L[(AsN + xoff) >> 1] = pack8(xa, xb);   // x(i+1)
        if (i < 30) {
          xa = *(const float4*)(xp + (i + 2) * 32);       // x(i+2) -> regs
          xb = *(const float4*)(xp + (i + 2) * 32 + 4);
        }
      }
    }
    bf16x8 av[4], bw3[3];
#pragma unroll
    for (int mi = 0; mi < 4; ++mi)
      av[mi] = *(const bf16x8*)&L[(AsC + mi * 1024 + qd * 256 + fr * 16) >> 1];
#pragma unroll
    for (int nj = 0; nj < 3; ++nj)
      bw3[nj] = *(const bf16x8*)&L[(BsC + (3 * w + nj) * 1024 + qd * 256 + fr * 16) >> 1];
#pragma unroll
    for (int mi = 0; mi < 4; ++mi)
#pragma unroll
      for (int nj = 0; nj < 3; ++nj)
        acc[mi][nj] = mf(av[mi], bw3[nj], acc[mi][nj]);
    __syncthreads();
  }

  // ---------------- distribute K/V/Q into fragment-panel layouts ------------
  float dp63[16];    // LR * d^{63-t}
#pragma unroll
  for (int mi = 0; mi < 4; ++mi)
#pragma unroll
    for (int r = 0; r < 4; ++r)
      dp63[mi * 4 + r] = kLR * exp2f((float)(63 - (mi * 16 + qd * 4 + r)) * kLog2d);

  const size_t qchunk = (size_t)(b * kNC + c) * 8192;   // u16 units (16 KiB/chunk)
#pragma unroll
  for (int nj = 0; nj < 3; ++nj) {
    const int pn = 3 * w + nj;          // 0..23, slab uniform per (w,nj)
    const int slab = pn >> 3;
    const int jj = (pn & 7) * 16 + fr;  // 0..127 within slab
    const float* bp = (slab == 0) ? bk : (slab == 1) ? bv : bq;
    const float bias = bp[jj];
#pragma unroll
    for (int mi = 0; mi < 4; ++mi)
#pragma unroll
      for (int r = 0; r < 4; ++r) {
        const int t = mi * 16 + qd * 4 + r;
        const float val = acc[mi][nj][r] + bias;
        const u16 h = f2bf(val);
        if (slab == 0) {
          L[(KsB + fo64x128(t, jj)) >> 1] = h;                               // K[t][j]
          L[(KwB + fo128x64(jj, t)) >> 1] = f2bf(val * dp63[mi * 4 + r]);    // Kw[j][t]
        } else if (slab == 1) {
          L[(VtB + fo128x64(jj, t)) >> 1] = h;                               // V^T[i][t]
        } else {
          L[(QsB + fo64x128(t, jj)) >> 1] = h;                               // Q[t][j]
          Qg[qchunk + (fo64x128(t, jj) >> 1)] = h;   // global Q in frag layout
        }
      }
  }
  __syncthreads();

  // ---------------- P = Q K^T (8 waves: tp = w>>1, u-pair = (w&1)*2) --------
  const int tp = w >> 1, up0 = (w & 1) * 2;
  f32x4 p2[2] = {};
  {
    bf16x8 aq[4];
#pragma unroll
    for (int kp = 0; kp < 4; ++kp)
      aq[kp] = *(const bf16x8*)&L[(QsB + (tp * 4 + kp) * 1024 + qd * 256 + fr * 16) >> 1];
#pragma unroll
    for (int ui = 0; ui < 2; ++ui)
#pragma unroll
      for (int kp = 0; kp < 4; ++kp) {
        bf16x8 bks = *(const bf16x8*)&L[(KsB + ((up0 + ui) * 4 + kp) * 1024 + qd * 256 + fr * 16) >> 1];
        p2[ui] = mf(aq[kp], bks, p2[ui]);
      }
  }
  __syncthreads();   // Ks reads done; reuse front half for At

  // ---------------- mask + decay -> At ----------------
#pragma unroll
  for (int ui = 0; ui < 2; ++ui)
#pragma unroll
    for (int r = 0; r < 4; ++r) {
      const int t = tp * 16 + qd * 4 + r;
      const int u = (up0 + ui) * 16 + fr;
      float av2 = 0.f;
      if (u < t) av2 = kLR * exp2f((float)(t - 1 - u) * kLog2d) * p2[ui][r];
      L[(AtB + fo64x64(t, u)) >> 1] = f2bf(av2);
    }
  __syncthreads();

  // ---------------- O1 = At V^T (tp, i-half) ; U = V^T Kw (i-panel = w) -----
  const int ip0 = (w & 1) * 4;
  f32x4 o1[4] = {}, uu[8] = {};
#pragma unroll
  for (int uc = 0; uc < 2; ++uc) {
    bf16x8 aA = *(const bf16x8*)&L[(AtB + (tp * 2 + uc) * 1024 + qd * 256 + fr * 16) >> 1];
    bf16x8 aV = *(const bf16x8*)&L[(VtB + (w * 2 + uc) * 1024 + qd * 256 + fr * 16) >> 1];
#pragma unroll
    for (int ni = 0; ni < 4; ++ni) {
      bf16x8 bV = *(const bf16x8*)&L[(VtB + ((ip0 + ni) * 2 + uc) * 1024 + qd * 256 + fr * 16) >> 1];
      o1[ni] = mf(aA, bV, o1[ni]);
    }
#pragma unroll
    for (int jp = 0; jp < 8; ++jp) {
      bf16x8 bK = *(const bf16x8*)&L[(KwB + (jp * 2 + uc) * 1024 + qd * 256 + fr * 16) >> 1];
      uu[jp] = mf(aV, bK, uu[jp]);
    }
  }

  // ---------------- epilogue stores ----------------
#pragma unroll
  for (int ni = 0; ni < 4; ++ni)
#pragma unroll
    for (int r = 0; r < 4; ++r) {
      const int t = tp * 16 + qd * 4 + r, i = (ip0 + ni) * 16 + fr;
      O1g[(size_t)(R0 + t) * kM + i] = f2bf(o1[ni][r]);
    }
  float* SUc = SU + (size_t)(b * kNC + c) * (kM * kM);
#pragma unroll
  for (int jp = 0; jp < 8; ++jp)
#pragma unroll
    for (int r = 0; r < 4; ++r) {
      const int i = w * 16 + qd * 4 + r, j = jp * 16 + fr;
      SUc[i * kM + j] = uu[jp][r];
    }
}

// ---------------------------------------------------------------------------
// inter-chunk scan: Sb16[c] = bf16(state before chunk c); carry -> state_out
// ---------------------------------------------------------------------------
__global__ __launch_bounds__(256)
void scan_kernel(const float* __restrict__ SU, u16* __restrict__ Sb16,
                 float* __restrict__ state_out)
{
  const int e = blockIdx.x * 256 + threadIdx.x;   // < kB * 16384
  const int b = e >> 14, ij = e & 16383;
  const float* base = SU + (size_t)b * kNC * 16384 + ij;
  u16* sb = Sb16 + (size_t)b * kNC * 16384 + ij;
  const float dC = exp2f((float)kC * kLog2d);
  float prev = 0.f;
#pragma unroll 8
  for (int c2 = 0; c2 < kNC; ++c2) {
    const float u = base[(size_t)c2 * 16384];
    sb[(size_t)c2 * 16384] = f2bf(prev);
    prev = fmaf(dC, prev, u);
  }
  state_out[e] = prev;
}

// ---------------------------------------------------------------------------
// Kernel B: fused combine + output GEMM, 512 threads (8 waves).
//   O2 = Q S^T ; Out = bf16(O1 + d^t O2) -> fragment panels
//   y  = Out @ Woh^T + bo  (B fragments read from global; Woh L2-hot)
// LDS (48 KiB): Qs @ 0 (16K frag panels, staged linearly from Qg),
//               Ss @ 16384 (32K frag panels); OutP reuses Qs region.
// ---------------------------------------------------------------------------
__global__ __launch_bounds__(512)
void fused_combine_out(const u16* __restrict__ Qg, const u16* __restrict__ Sb16,
                       const u16* __restrict__ O1g, const u16* __restrict__ Woh,
                       const float* __restrict__ bo, float* __restrict__ y)
{
  __shared__ __align__(16) u16 L[24576];
  const int c = blockIdx.x, b = blockIdx.y;
  const int R0 = b * kS + c * kC;
  const int tid = threadIdx.x, w = tid >> 6, lane = tid & 63;
  const int fr = lane & 15, qd = lane >> 4;
  constexpr int QsB = 0, SsB = 16384, OutB = 0;
  const size_t chunk = (size_t)(b * kNC + c);

  // stage Q (frag-layout in global -> identity copy, 2 panels/wave)
  const u16* Qgc = Qg + chunk * 8192;
#pragma unroll
  for (int g = 0; g < 2; ++g)
    gl_lds16(Qgc + (2 * w + g) * 512 + lane * 8, &L[(QsB + (2 * w + g) * 1024) >> 1]);
  // stage S (row-major global, per-lane src in fragment order, 4 panels/wave)
  const u16* Sbc = Sb16 + chunk * 16384;
#pragma unroll
  for (int g = 0; g < 4; ++g) {
    const int pn = 4 * w + g, ip = pn >> 2, kc = pn & 3;
    gl_lds16(Sbc + (size_t)(ip * 16 + fr) * kM + kc * 32 + qd * 8,
             &L[(SsB + pn * 1024) >> 1]);
  }

  const int tp = w >> 1, ip0 = (w & 1) * 4;
  // prefetch O1 (matches C-layout positions), overlaps staging
  u16 o1h[4][4];
#pragma unroll
  for (int ni = 0; ni < 4; ++ni)
#pragma unroll
    for (int r = 0; r < 4; ++r)
      o1h[ni][r] =
          O1g[(size_t)(R0 + tp * 16 + qd * 4 + r) * kM + (ip0 + ni) * 16 + fr];
  __syncthreads();

  // O2 = Q S^T
  f32x4 o2[4] = {};
  {
    bf16x8 aq[4];
#pragma unroll
    for (int kp = 0; kp < 4; ++kp)
      aq[kp] = *(const bf16x8*)&L[(QsB + (tp * 4 + kp) * 1024 + qd * 256 + fr * 16) >> 1];
#pragma unroll
    for (int ni = 0; ni < 4; ++ni)
#pragma unroll
      for (int kp = 0; kp < 4; ++kp) {
        bf16x8 bS = *(const bf16x8*)&L[(SsB + ((ip0 + ni) * 4 + kp) * 1024 + qd * 256 + fr * 16) >> 1];
        o2[ni] = mf(aq[kp], bS, o2[ni]);
      }
  }
  __syncthreads();   // Qs reads done; reuse region for Out panels

  // Out = bf16(O1 + d^t * O2)
#pragma unroll
  for (int r = 0; r < 4; ++r) {
    const int t = tp * 16 + qd * 4 + r;
    const float dt = exp2f((float)t * kLog2d);
#pragma unroll
    for (int ni = 0; ni < 4; ++ni) {
      const int i = (ip0 + ni) * 16 + fr;
      const float ov = fmaf(dt, o2[ni][r], bf2f(o1h[ni][r]));
      L[(OutB + fo64x128(t, i)) >> 1] = f2bf(ov);
    }
  }
  __syncthreads();

  // y = Out @ Woh^T + bo; wave covers d in [128w, 128w+128), 2 halves of 64
#pragma unroll 1
  for (int h = 0; h < 2; ++h) {
    const int n0 = w * 128 + h * 64;
    f32x4 fy[4][4] = {};
#pragma unroll
    for (int kp = 0; kp < 4; ++kp) {
      bf16x8 ao[4], bw[4];
#pragma unroll
      for (int mi = 0; mi < 4; ++mi)
        ao[mi] = *(const bf16x8*)&L[(OutB + (mi * 4 + kp) * 1024 + qd * 256 + fr * 16) >> 1];
#pragma unroll
      for (int dp = 0; dp < 4; ++dp)
        bw[dp] = *(const bf16x8*)&Woh[(size_t)(n0 + dp * 16 + fr) * kM + kp * 32 + qd * 8];
#pragma unroll
      for (int mi = 0; mi < 4; ++mi)
#pragma unroll
        for (int dp = 0; dp < 4; ++dp)
          fy[mi][dp] = mf(ao[mi], bw[dp], fy[mi][dp]);
    }
#pragma unroll
    for (int dp = 0; dp < 4; ++dp) {
      const int d = n0 + dp * 16 + fr;
      const float bb = bo[d];
#pragma unroll
      for (int mi = 0; mi < 4; ++mi)
#pragma unroll
        for (int r = 0; r < 4; ++r)
          y[(size_t)(R0 + mi * 16 + qd * 4 + r) * kD + d] = fy[mi][dp][r] + bb;
    }
  }
}

// ---------------------------------------------------------------------------
extern "C" void kernel_launch(void* const* d_in, const int* in_sizes, int n_in,
                              void* d_out, int out_size, void* d_ws, size_t ws_size,
                              hipStream_t stream) {
  const float* x  = (const float*)d_in[0];
  const float* Wk = (const float*)d_in[1];
  const float* bk = (const float*)d_in[2];
  const float* Wv = (const float*)d_in[3];
  const float* bv = (const float*)d_in[4];
  const float* Wq = (const float*)d_in[5];
  const float* bq = (const float*)d_in[6];
  const float* Wo = (const float*)d_in[7];
  const float* bo = (const float*)d_in[8];

  char* wsp = (char*)d_ws;
  u16* Wkvq = (u16*)wsp;   wsp += (size_t)384 * 1024 * 2;
  u16* Woh  = (u16*)wsp;   wsp += (size_t)1024 * 128 * 2;
  u16* Qg   = (u16*)wsp;   wsp += (size_t)kRS * kM * 2;
  u16* O1g  = (u16*)wsp;   wsp += (size_t)kRS * kM * 2;
  float* SU = (float*)wsp; wsp += (size_t)kB * kNC * 16384 * 4;
  u16* Sb16 = (u16*)wsp;   wsp += (size_t)kB * kNC * 16384 * 2;

  float* y = (float*)d_out;
  float* state_out = y + (size_t)kRS * kD;

  cast_w_kernel<<<dim3(512), dim3(256), 0, stream>>>(Wk, Wv, Wq, Wo, Wkvq, Woh);
  fused_proj_intra<<<dim3(kNC, kB), dim3(512), 0, stream>>>(x, Wkvq, bk, bv, bq, Qg, O1g, SU);
  scan_kernel<<<dim3(kB * 16384 / 256), dim3(256), 0, stream>>>(SU, Sb16, state_out);
  fused_combine_out<<<dim3(kNC, kB), dim3(512), 0, stream>>>(Qg, Sb16, O1g, Woh, bo, y);
}